// Round 7
// baseline (6336.049 us; speedup 1.0000x reference)
//
#include <hip/hip_runtime.h>

// TreeLSTM (B=256, T=128, E=256, D=256) for MI355X / gfx950 — v5.
//
// v5 changes (rocprof-driven, vs v4 @ 2249 us):
//  * plan_kernel: v4's lambda-based stack was alloca->LDS-promoted
//    (VGPR=16, LDS=8192, 230 us). Rewritten with straight-line macros and
//    ternary selects only -> true register residency.
//  * front_kernel: v4 kept VGPR=148 / 11% occupancy (16 f32x4 accumulators).
//    Now NT=4 (64 cols/block, 8 accumulators), grid (2048,4) -> lower VGPR,
//    ~2x occupancy. xpk dropped (didn't address the real bottleneck).
//  * THE BIG ONE: 128 per-step launches (~1600 us) -> ONE persistent
//    scan_kernel, grid (32 chunks, 16 groups), 1 wave/wg (512 wg, 2/CU —
//    co-residency guaranteed). Serial dependency spans only the 32 chunk-wgs
//    of a batch-group, so phases are separated by GROUP-scoped device
//    barriers: monotonic per-group counter (128B-padded), agent-scope
//    atomic arrive + acquire spin + __threadfence on both sides.
//    Cell math identical to v4's passing step_kernel (K=512 self-contained;
//    no Ppre, no ws_size-dependent ring).
//  * Fallback: if ws_size lacks the 2KB barrier page, per-step launches.
//
// Workspace layout (fixed = 87,426,048 B + 2,048 B barriers):
//   Wr_t  u32 [1280][512]        2,621,440 @ 0
//   Wpg   u32 [512][256]           524,288 @ 2,621,440
//   h_buf u32 [32768][256]      33,554,432 @ 3,145,728
//   c_buf f32 [32768][256]      33,554,432 @ 36,700,160
//   vstkH u32 [32][256][256]     8,388,608 @ 70,254,592   (slot 31 = zeros)
//   vstkC f32 [32][256][256]     8,388,608 @ 78,643,200
//   planL/R/W i32 [128][256]   3 x 131,072 @ 87,031,808
//   fdesc i32 [256]                  1,024 @ 87,425,024
//   bar   u32 [16][32] (padded)      2,048 @ 87,426,048

typedef unsigned int u32;
typedef short s16x8 __attribute__((ext_vector_type(8)));
typedef float f32x4 __attribute__((ext_vector_type(4)));

#define NPAIR 128

#define MFMA16(a, b, c) __builtin_amdgcn_mfma_f32_16x16x32_bf16((a), (b), (c), 0, 0, 0)

static __device__ __forceinline__ unsigned short f2bf(float x) {
  u32 u = __builtin_bit_cast(u32, x);
  u += 0x7fffu + ((u >> 16) & 1u);  // round-to-nearest-even
  return (unsigned short)(u >> 16);
}
static __device__ __forceinline__ float bf2f(unsigned short s) {
  u32 u = ((u32)s) << 16;
  return __builtin_bit_cast(float, u);
}
static __device__ __forceinline__ u32 packhl(float x) {
  unsigned short hi = f2bf(x);
  unsigned short lo = f2bf(x - bf2f(hi));
  return ((u32)hi << 16) | (u32)lo;
}
static __device__ __forceinline__ float unpackhl(u32 p) {
  return bf2f((unsigned short)(p >> 16)) + bf2f((unsigned short)(p & 0xffffu));
}
static __device__ __forceinline__ void unpack8(uint4 a, uint4 b, s16x8 &hi, s16x8 &lo) {
  hi[0] = (short)(a.x >> 16); lo[0] = (short)a.x;
  hi[1] = (short)(a.y >> 16); lo[1] = (short)a.y;
  hi[2] = (short)(a.z >> 16); lo[2] = (short)a.z;
  hi[3] = (short)(a.w >> 16); lo[3] = (short)a.w;
  hi[4] = (short)(b.x >> 16); lo[4] = (short)b.x;
  hi[5] = (short)(b.y >> 16); lo[5] = (short)b.y;
  hi[6] = (short)(b.z >> 16); lo[6] = (short)b.z;
  hi[7] = (short)(b.w >> 16); lo[7] = (short)b.w;
}
static __device__ __forceinline__ void split8(const float *w, s16x8 &hi, s16x8 &lo) {
#pragma unroll
  for (int i = 0; i < 8; i++) {
    unsigned short h = f2bf(w[i]);
    hi[i] = (short)h;
    lo[i] = (short)f2bf(w[i] - bf2f(h));
  }
}
static __device__ __forceinline__ float sigm(float x) { return 1.0f / (1.0f + expf(-x)); }
// value-slot index from 16-bit code: pos=code&15, ver=(code>>4)&1 -> slot=pos*2+ver
static __device__ __forceinline__ int vslot(int code) {
  return (code & 15) * 2 + ((code >> 4) & 1);
}

// ---------------------------------------------------------------- pack
__global__ __launch_bounds__(256) void pack_kernel(
    const float *__restrict__ Wp, const float *__restrict__ Wg,
    const float *__restrict__ Wr, u32 *__restrict__ Wpg_t,
    u32 *__restrict__ Wr_t, u32 *__restrict__ vstkH, float *__restrict__ vstkC,
    u32 *__restrict__ bar, int do_bar) {
  int tid = blockIdx.x * 256 + threadIdx.x;
  if (tid < 131072) {  // Wp|Wg: each [256 E][256 D]; write Wpg_t[col][k]
    int isg = tid >= 65536;
    int s = tid & 65535;
    int k = s >> 8, col = s & 255;
    float v = isg ? Wg[s] : Wp[s];
    Wpg_t[(isg ? 256 + col : col) * 256 + k] = packhl(v);
  }
  if (tid < 655360) {  // Wr [512][1280] read-linear, write Wr_t[col][k]
    int k = tid / 1280;
    int col = tid - k * 1280;
    Wr_t[col * 512 + k] = packhl(Wr[tid]);
  }
  if (tid < 65536) {  // zero value-slot 31 (ZCODE target / dummy-A zeros)
    vstkH[31 * 65536 + tid] = 0u;
    vstkC[31 * 65536 + tid] = 0.0f;
  }
  if (do_bar && tid < 512) bar[tid] = 0u;  // barrier counters
}

// ---------------------------------------------------------------- plan
// Straight-line register-packed symbolic stack: 16 entries x 8 bits in
// t0..t3 (ternary selects only — NO lambdas/arrays: v4's lambdas were
// alloca->LDS-promoted, 230 us). entry: bit7=1 -> value slot (bits0-3 pos,
// bit4 ver); bit7=0 -> buffer row.
#define PGET(p, dst)                                                         \
  {                                                                          \
    u32 wsel = ((p) & 8) ? (((p) & 4) ? t3 : t2) : (((p) & 4) ? t1 : t0);    \
    dst = (int)((wsel >> (((p) & 3) * 8)) & 0xffu);                          \
  }
#define PSET(p, e)                                                           \
  {                                                                          \
    u32 sh_ = (u32)((p) & 3) * 8u;                                           \
    u32 m_ = ~(0xffu << sh_);                                                \
    u32 nv_ = ((u32)(e)) << sh_;                                             \
    int w_ = (p) >> 2;                                                       \
    t0 = (w_ == 0) ? ((t0 & m_) | nv_) : t0;                                 \
    t1 = (w_ == 1) ? ((t1 & m_) | nv_) : t1;                                 \
    t2 = (w_ == 2) ? ((t2 & m_) | nv_) : t2;                                 \
    t3 = (w_ == 3) ? ((t3 & m_) | nv_) : t3;                                 \
  }
#define PDOSTEP(tr, l, r, w)                                                 \
  {                                                                          \
    if ((tr) == 0) {                                                         \
      int pos_ = min(ptr, 15);                                               \
      PSET(pos_, (u32)(bptr & 127));                                         \
      ptr++;                                                                 \
      bptr--;                                                                \
    } else {                                                                 \
      int pl_ = min(max(ptr - 2, 0), 15);                                    \
      int pr_ = min(max(ptr - 1, 0), 15);                                    \
      PGET(pl_, l);                                                          \
      PGET(pr_, r);                                                          \
      u32 v_ = ((verb >> pl_) & 1u) ^ 1u;                                    \
      verb = (verb & ~(1u << pl_)) | (v_ << pl_);                            \
      PSET(pl_, 0x80u | (v_ << 4) | (u32)pl_);                               \
      w = pl_ * 2 + (int)v_;                                                 \
      ptr--;                                                                 \
    }                                                                        \
  }

__global__ __launch_bounds__(256) void plan_kernel(
    const int *__restrict__ trans, int *__restrict__ pL, int *__restrict__ pR,
    int *__restrict__ pW, int *__restrict__ fdesc) {
  int b = threadIdx.x;
  u32 t0 = 0x9F9F9F9Fu, t1 = 0x9F9F9F9Fu, t2 = 0x9F9F9F9Fu, t3 = 0x9F9F9F9Fu;
  u32 verb = 0;
  int ptr = 0, bptr = 127;

  for (int f = 0; f < NPAIR; ++f) {
    int trA = trans[(2 * f) * 256 + b];
    int trB = (2 * f + 1 < 255) ? trans[(2 * f + 1) * 256 + b] : -1;
    int l = 0x9F, r = 0x9F, w = -1;
    PDOSTEP(trA, l, r, w);
    if (trB >= 0) PDOSTEP(trB, l, r, w);
    pL[f * 256 + b] = (l & 0x80) ? (0x8000 | (l & 0x1f)) : l;
    pR[f * 256 + b] = (r & 0x80) ? (0x8000 | (r & 0x1f)) : r;
    pW[f * 256 + b] = w;
  }
  int pf = min(max(ptr - 1, 0), 15);
  int fd;
  PGET(pf, fd);
  fdesc[b] = (fd & 0x80) ? (0x8000 | (fd & 0x1f)) : fd;
}

// ---------------------------------------------------------------- front GEMM
// 1 wave per wg; tile M=16 x 64 d-cols (NT=4) of BOTH Wp and Wg panels.
__global__ __launch_bounds__(64) void front_kernel(
    const float *__restrict__ x, const u32 *__restrict__ Wpg,
    const float *__restrict__ bp, const float *__restrict__ bg,
    u32 *__restrict__ h_buf, float *__restrict__ c_buf) {
  const int lane = threadIdx.x;
  const int rbase = blockIdx.x * 16;
  const int y = blockIdx.y;  // 0..3 -> d cols [y*64, y*64+64)
  const int rlo = lane & 15;
  const int khi = (lane >> 4) * 8;

  f32x4 z = {0.f, 0.f, 0.f, 0.f};
  f32x4 aP[4], aG[4];
#pragma unroll
  for (int i = 0; i < 4; i++) { aP[i] = z; aG[i] = z; }

#pragma unroll 2
  for (int kt = 0; kt < 8; ++kt) {
    int k = kt * 32 + khi;
    s16x8 Ah, Al;
    {
      const float *ap = x + (rbase + rlo) * 256 + k;
      float4 v0 = *(const float4 *)ap;
      float4 v1 = *(const float4 *)(ap + 4);
      float w[8] = {v0.x, v0.y, v0.z, v0.w, v1.x, v1.y, v1.z, v1.w};
      split8(w, Ah, Al);
    }
#pragma unroll
    for (int nt = 0; nt < 4; ++nt) {
      int colP = y * 64 + nt * 16 + rlo;
      {
        const u32 *wp = Wpg + colP * 256 + k;
        uint4 q0 = *(const uint4 *)wp, q1 = *(const uint4 *)(wp + 4);
        s16x8 Bh, Bl;
        unpack8(q0, q1, Bh, Bl);
        aP[nt] = MFMA16(Ah, Bh, aP[nt]);
        aP[nt] = MFMA16(Ah, Bl, aP[nt]);
        aP[nt] = MFMA16(Al, Bh, aP[nt]);
      }
      {
        const u32 *wg = Wpg + (256 + colP) * 256 + k;
        uint4 q0 = *(const uint4 *)wg, q1 = *(const uint4 *)(wg + 4);
        s16x8 Bh, Bl;
        unpack8(q0, q1, Bh, Bl);
        aG[nt] = MFMA16(Ah, Bh, aG[nt]);
        aG[nt] = MFMA16(Ah, Bl, aG[nt]);
        aG[nt] = MFMA16(Al, Bh, aG[nt]);
      }
    }
  }
  // epilogue: C/D col=lane&15, row=(lane>>4)*4+reg
#pragma unroll
  for (int nt = 0; nt < 4; ++nt) {
    int d = y * 64 + nt * 16 + rlo;
    float bpd = bp[d], bgd = bg[d];
#pragma unroll
    for (int ri = 0; ri < 4; ++ri) {
      int r = rbase + (lane >> 4) * 4 + ri;
      float cv = aP[nt][ri] + bpd;
      float gv = aG[nt][ri] + bgd;
      c_buf[r * 256 + d] = cv;
      h_buf[r * 256 + d] = packhl(sigm(gv) * tanhf(cv));
    }
  }
}

// ---------------------------------------------------------------- step body
// One fused pair for chunk c, batch-group b0 (v4's passing PPRE=0 logic).
#define KSTEP_BODY(SRC, KOFF)                                                \
  {                                                                          \
    const u32 *s = (SRC) + kt * 32 + khi;                                    \
    uint4 a0 = *(const uint4 *)s, a1 = *(const uint4 *)(s + 4);              \
    s16x8 Ah, Al;                                                            \
    unpack8(a0, a1, Ah, Al);                                                 \
    int kk = (KOFF) + kt * 32 + khi;                                         \
    {                                                                        \
      const u32 *wp = Wr_t + gcol0 * 512 + kk;                               \
      uint4 q0 = *(const uint4 *)wp, q1 = *(const uint4 *)(wp + 4);          \
      s16x8 Bh, Bl;                                                          \
      unpack8(q0, q1, Bh, Bl);                                               \
      acc0 = MFMA16(Ah, Bh, acc0);                                           \
      acc0 = MFMA16(Ah, Bl, acc0);                                           \
      acc0 = MFMA16(Al, Bh, acc0);                                           \
    }                                                                        \
    {                                                                        \
      const u32 *wp = Wr_t + gcol1 * 512 + kk;                               \
      uint4 q0 = *(const uint4 *)wp, q1 = *(const uint4 *)(wp + 4);          \
      s16x8 Bh, Bl;                                                          \
      unpack8(q0, q1, Bh, Bl);                                               \
      acc1 = MFMA16(Ah, Bh, acc1);                                           \
      acc1 = MFMA16(Ah, Bl, acc1);                                           \
      acc1 = MFMA16(Al, Bh, acc1);                                           \
    }                                                                        \
    {                                                                        \
      const u32 *wp = Wr_t + gcol2 * 512 + kk;                               \
      uint4 q0 = *(const uint4 *)wp, q1 = *(const uint4 *)(wp + 4);          \
      s16x8 Bh, Bl;                                                          \
      unpack8(q0, q1, Bh, Bl);                                               \
      acc2 = MFMA16(Ah, Bh, acc2);                                           \
      acc2 = MFMA16(Ah, Bl, acc2);                                           \
      acc2 = MFMA16(Al, Bh, acc2);                                           \
    }                                                                        \
  }

static __device__ __forceinline__ void step_body(
    int c, int b0, int lane, const float *__restrict__ br,
    const u32 *__restrict__ Wr_t, const u32 *__restrict__ h_buf,
    const float *__restrict__ c_buf, u32 *__restrict__ vstkH,
    float *__restrict__ vstkC, int lc, int rc, int w) {
  const int b = b0 + (lane & 15);
  const bool lval = (lc & 0x8000) != 0;
  const bool rval = (rc & 0x8000) != 0;
  const u32 *srcT = lval ? vstkH + ((vslot(lc) * 256 + b) << 8)
                         : h_buf + (((b << 7) + (lc & 127)) << 8);
  const u32 *srcB = rval ? vstkH + ((vslot(rc) * 256 + b) << 8)
                         : h_buf + (((b << 7) + (rc & 127)) << 8);

  const int khi = (lane >> 4) * 8;
  const int cl = lane & 15;
  const int v2c = 32 + cl;
  const int gcol0 = (cl >> 3) * 256 + c * 8 + (cl & 7);
  const int gcol1 = ((16 + cl) >> 3) * 256 + c * 8 + (cl & 7);
  const int gcol2 = (v2c < 40) ? (v2c >> 3) * 256 + c * 8 + (v2c & 7) : 0;

  f32x4 acc0 = {0.f, 0.f, 0.f, 0.f}, acc1 = acc0, acc2 = acc0;
#pragma unroll 4
  for (int kt = 0; kt < 8; ++kt) KSTEP_BODY(srcT, 0)
#pragma unroll 4
  for (int kt = 0; kt < 8; ++kt) KSTEP_BODY(srcB, 256)

  // cell: out-dim j: i=acc0[col j], f_l=acc0[col 8+j], f_r=acc1[col j],
  //       g=acc1[col 8+j], o=acc2[col j]; C/D row=(lane>>4)*4+reg
  f32x4 flv, gv;
#pragma unroll
  for (int ri = 0; ri < 4; ++ri) {
    flv[ri] = __shfl_xor(acc0[ri], 8);
    gv[ri] = __shfl_xor(acc1[ri], 8);
  }
  int lcs[4], rcs[4], wcs[4];
#pragma unroll
  for (int ri = 0; ri < 4; ++ri) {
    int rr = (lane >> 4) * 4 + ri;
    lcs[ri] = __shfl(lc, rr);
    rcs[ri] = __shfl(rc, rr);
    wcs[ri] = __shfl(w, rr);
  }
  int colj = lane & 15;
  if (colj < 8) {
    int d = c * 8 + colj;
    float brI = br[d], brFl = br[256 + d], brFr = br[512 + d];
    float brG = br[768 + d], brO = br[1024 + d];
#pragma unroll
    for (int ri = 0; ri < 4; ++ri) {
      if (wcs[ri] >= 0) {
        int b2 = b0 + (lane >> 4) * 4 + ri;
        int lc2 = lcs[ri], rc2 = rcs[ri];
        float c_l = (lc2 & 0x8000)
                        ? vstkC[(vslot(lc2) * 256 + b2) * 256 + d]
                        : c_buf[(b2 * 128 + (lc2 & 127)) * 256 + d];
        float c_r = (rc2 & 0x8000)
                        ? vstkC[(vslot(rc2) * 256 + b2) * 256 + d]
                        : c_buf[(b2 * 128 + (rc2 & 127)) * 256 + d];
        float ii = acc0[ri] + brI;
        float fl = flv[ri] + brFl;
        float fr = acc1[ri] + brFr;
        float gg = gv[ri] + brG;
        float oo = acc2[ri] + brO;
        float cv = sigm(ii) * tanhf(gg) + sigm(fl) * c_l + sigm(fr) * c_r;
        float hv = sigm(oo) * tanhf(cv);
        int sidx = wcs[ri];
        vstkH[(sidx * 256 + b2) * 256 + d] = packhl(hv);
        vstkC[(sidx * 256 + b2) * 256 + d] = cv;
      }
    }
  }
}

// ---------------------------------------------------------------- scan
// ONE launch for all 128 pairs. grid (32 chunks, 16 groups), 64 thr (1 wave).
// 512 wg, <=2/CU: co-residency guaranteed. Phase separation via GROUP-scoped
// monotonic barrier (the serial dep spans only the group's 32 chunk-wgs).
__global__ __launch_bounds__(64) void scan_kernel(
    const float *__restrict__ br, const u32 *__restrict__ Wr_t,
    const u32 *__restrict__ h_buf, const float *__restrict__ c_buf,
    u32 *__restrict__ vstkH, float *__restrict__ vstkC,
    const int *__restrict__ pL, const int *__restrict__ pR,
    const int *__restrict__ pW, u32 *bar) {
  const int c = blockIdx.x;
  const int g = blockIdx.y;
  const int lane = threadIdx.x;
  const int b0 = g * 16;
  u32 *mybar = bar + g * 32;  // 128B-padded per-group counter

  for (int f = 0; f < NPAIR; ++f) {
    int lc = 0, rc = 0, w = -1;
    if (lane < 16) {
      int b = b0 + lane;
      lc = pL[f * 256 + b];
      rc = pR[f * 256 + b];
      w = pW[f * 256 + b];
    }
    // broadcast to full wave (row = lane&15)
    lc = __shfl(lc, lane & 15);
    rc = __shfl(rc, lane & 15);
    w = __shfl(w, lane & 15);

    if (__ballot(w >= 0) != 0ull)
      step_body(c, b0, lane, br, Wr_t, h_buf, c_buf, vstkH, vstkC, lc, rc, w);

    // group barrier: release own vstk writes, arrive, spin, acquire
    __threadfence();
    if (lane == 0) {
      __hip_atomic_fetch_add(mybar, 1u, __ATOMIC_RELEASE, __HIP_MEMORY_SCOPE_AGENT);
      u32 tgt = 32u * (u32)(f + 1);
      while (__hip_atomic_load(mybar, __ATOMIC_ACQUIRE, __HIP_MEMORY_SCOPE_AGENT) < tgt)
        __builtin_amdgcn_s_sleep(1);
    }
    __threadfence();
  }
}

// ---------------------------------------------------------------- fallback step
__global__ __launch_bounds__(64) void step_kernel(
    const float *__restrict__ br, const u32 *__restrict__ Wr_t,
    const u32 *__restrict__ h_buf, const float *__restrict__ c_buf,
    u32 *__restrict__ vstkH, float *__restrict__ vstkC,
    const int *__restrict__ pL, const int *__restrict__ pR,
    const int *__restrict__ pW) {
  const int c = blockIdx.x;
  const int b0 = blockIdx.y * 16;
  const int lane = threadIdx.x;
  int lc = 0, rc = 0, w = -1;
  if (lane < 16) {
    int b = b0 + lane;
    lc = pL[b];
    rc = pR[b];
    w = pW[b];
  }
  lc = __shfl(lc, lane & 15);
  rc = __shfl(rc, lane & 15);
  w = __shfl(w, lane & 15);
  if (__ballot(w >= 0) == 0ull) return;
  step_body(c, b0, lane, br, Wr_t, h_buf, c_buf, vstkH, vstkC, lc, rc, w);
}

// ---------------------------------------------------------------- output
__global__ __launch_bounds__(256) void out_kernel(
    const int *__restrict__ fdesc, const u32 *__restrict__ h_buf,
    const u32 *__restrict__ vstkH, float *__restrict__ out) {
  int tid = blockIdx.x * 256 + threadIdx.x;  // 65536
  int b = tid >> 8, d = tid & 255;
  int code = fdesc[b];
  u32 hv = (code & 0x8000)
               ? vstkH[(vslot(code) * 256 + b) * 256 + d]
               : h_buf[(b * 128 + (code & 127)) * 256 + d];
  out[tid] = unpackhl(hv);
}

// ---------------------------------------------------------------- launch
extern "C" void kernel_launch(void *const *d_in, const int *in_sizes, int n_in,
                              void *d_out, int out_size, void *d_ws, size_t ws_size,
                              hipStream_t stream) {
  const float *x = (const float *)d_in[0];
  const float *Wp = (const float *)d_in[1];
  const float *bp = (const float *)d_in[2];
  const float *Wg = (const float *)d_in[3];
  const float *bg = (const float *)d_in[4];
  const float *Wr = (const float *)d_in[5];
  const float *br = (const float *)d_in[6];
  const int *trans = (const int *)d_in[7];
  float *out = (float *)d_out;

  char *ws = (char *)d_ws;
  u32 *Wr_t = (u32 *)(ws);
  u32 *Wpg = (u32 *)(ws + 2621440);
  u32 *h_buf = (u32 *)(ws + 3145728);
  float *c_buf = (float *)(ws + 36700160);
  u32 *vstkH = (u32 *)(ws + 70254592);
  float *vstkC = (float *)(ws + 78643200);
  int *planL = (int *)(ws + 87031808);
  int *planR = (int *)(ws + 87162880);
  int *planW = (int *)(ws + 87293952);
  int *fdesc = (int *)(ws + 87425024);
  u32 *bar = (u32 *)(ws + 87426048);

  const int use_scan = (ws_size >= (size_t)87426048 + 2048) ? 1 : 0;

  pack_kernel<<<2560, 256, 0, stream>>>(Wp, Wg, Wr, Wpg, Wr_t, vstkH, vstkC,
                                        bar, use_scan);
  plan_kernel<<<1, 256, 0, stream>>>(trans, planL, planR, planW, fdesc);
  front_kernel<<<dim3(2048, 4), 64, 0, stream>>>(x, Wpg, bp, bg, h_buf, c_buf);

  if (use_scan) {
    scan_kernel<<<dim3(32, 16), 64, 0, stream>>>(br, Wr_t, h_buf, c_buf, vstkH,
                                                 vstkC, planL, planR, planW, bar);
  } else {
    for (int f = 0; f < NPAIR; ++f)
      step_kernel<<<dim3(32, 16), 64, 0, stream>>>(
          br, Wr_t, h_buf, c_buf, vstkH, vstkC, planL + f * 256,
          planR + f * 256, planW + f * 256);
  }
  out_kernel<<<256, 256, 0, stream>>>(fdesc, h_buf, vstkH, out);
}

// Round 8
// 2352.660 us; speedup vs baseline: 2.6931x; 2.6931x over previous
//
#include <hip/hip_runtime.h>

// TreeLSTM (B=256, T=128, E=256, D=256) for MI355X / gfx950 — v6.
//
// v6 vs v5 (rocprof-driven): v5's persistent scan spent 47 us/phase because
// __threadfence() (agent scope, multi-XCD) emits L2 writeback+invalidate ->
// Wr_t (2.6 MB) refetched from HBM every phase (FETCH_SIZE 397 MB/dispatch).
// v6 removes ALL fences. Cross-wg vstk traffic goes through the device
// coherence point (MALL) via RELAXED+AGENT __hip_atomic load/store (sc-bit
// cache-bypassing ops, no cache maintenance); everything else (Wr_t, h_buf,
// c_buf, plan) uses normal cached vector loads and stays L2-resident.
// Barrier = s_waitcnt vmcnt(0) + relaxed agent fetch_add + relaxed spin.
//
// Workspace layout (fixed = 87,426,048 B + 2,048 B barriers):
//   Wr_t  u32 [1280][512]        2,621,440 @ 0
//   Wpg   u32 [512][256]           524,288 @ 2,621,440
//   h_buf u32 [32768][256]      33,554,432 @ 3,145,728
//   c_buf f32 [32768][256]      33,554,432 @ 36,700,160
//   vstkH u32 [32][256][256]     8,388,608 @ 70,254,592   (slot 31 = zeros)
//   vstkC f32 [32][256][256]     8,388,608 @ 78,643,200
//   planL/R/W i32 [128][256]   3 x 131,072 @ 87,031,808
//   fdesc i32 [256]                  1,024 @ 87,425,024
//   bar   u32 [16][32] (padded)      2,048 @ 87,426,048

typedef unsigned int u32;
typedef unsigned long long u64;
typedef short s16x8 __attribute__((ext_vector_type(8)));
typedef float f32x4 __attribute__((ext_vector_type(4)));

#define NPAIR 128

#define MFMA16(a, b, c) __builtin_amdgcn_mfma_f32_16x16x32_bf16((a), (b), (c), 0, 0, 0)

static __device__ __forceinline__ unsigned short f2bf(float x) {
  u32 u = __builtin_bit_cast(u32, x);
  u += 0x7fffu + ((u >> 16) & 1u);  // round-to-nearest-even
  return (unsigned short)(u >> 16);
}
static __device__ __forceinline__ float bf2f(unsigned short s) {
  u32 u = ((u32)s) << 16;
  return __builtin_bit_cast(float, u);
}
static __device__ __forceinline__ u32 packhl(float x) {
  unsigned short hi = f2bf(x);
  unsigned short lo = f2bf(x - bf2f(hi));
  return ((u32)hi << 16) | (u32)lo;
}
static __device__ __forceinline__ float unpackhl(u32 p) {
  return bf2f((unsigned short)(p >> 16)) + bf2f((unsigned short)(p & 0xffffu));
}
static __device__ __forceinline__ void unpack8(uint4 a, uint4 b, s16x8 &hi, s16x8 &lo) {
  hi[0] = (short)(a.x >> 16); lo[0] = (short)a.x;
  hi[1] = (short)(a.y >> 16); lo[1] = (short)a.y;
  hi[2] = (short)(a.z >> 16); lo[2] = (short)a.z;
  hi[3] = (short)(a.w >> 16); lo[3] = (short)a.w;
  hi[4] = (short)(b.x >> 16); lo[4] = (short)b.x;
  hi[5] = (short)(b.y >> 16); lo[5] = (short)b.y;
  hi[6] = (short)(b.z >> 16); lo[6] = (short)b.z;
  hi[7] = (short)(b.w >> 16); lo[7] = (short)b.w;
}
static __device__ __forceinline__ void split8(const float *w, s16x8 &hi, s16x8 &lo) {
#pragma unroll
  for (int i = 0; i < 8; i++) {
    unsigned short h = f2bf(w[i]);
    hi[i] = (short)h;
    lo[i] = (short)f2bf(w[i] - bf2f(h));
  }
}
static __device__ __forceinline__ float sigm(float x) { return 1.0f / (1.0f + expf(-x)); }
static __device__ __forceinline__ int vslot(int code) {
  return (code & 15) * 2 + ((code >> 4) & 1);
}

// ---- device-coherent (MALL) accessors: relaxed agent atomics, no fences ----
static __device__ __forceinline__ u32 cload32(const u32 *p) {
  return __hip_atomic_load(p, __ATOMIC_RELAXED, __HIP_MEMORY_SCOPE_AGENT);
}
static __device__ __forceinline__ u64 cload64(const u64 *p) {
  return __hip_atomic_load(p, __ATOMIC_RELAXED, __HIP_MEMORY_SCOPE_AGENT);
}
static __device__ __forceinline__ float cloadf(const float *p) {
  return __hip_atomic_load(p, __ATOMIC_RELAXED, __HIP_MEMORY_SCOPE_AGENT);
}
static __device__ __forceinline__ void cstore32(u32 *p, u32 v) {
  __hip_atomic_store(p, v, __ATOMIC_RELAXED, __HIP_MEMORY_SCOPE_AGENT);
}
static __device__ __forceinline__ void cstoref(float *p, float v) {
  __hip_atomic_store(p, v, __ATOMIC_RELAXED, __HIP_MEMORY_SCOPE_AGENT);
}

// ---------------------------------------------------------------- pack
__global__ __launch_bounds__(256) void pack_kernel(
    const float *__restrict__ Wp, const float *__restrict__ Wg,
    const float *__restrict__ Wr, u32 *__restrict__ Wpg_t,
    u32 *__restrict__ Wr_t, u32 *__restrict__ vstkH, float *__restrict__ vstkC,
    u32 *__restrict__ bar, int do_bar) {
  int tid = blockIdx.x * 256 + threadIdx.x;
  if (tid < 131072) {  // Wp|Wg: each [256 E][256 D]; write Wpg_t[col][k]
    int isg = tid >= 65536;
    int s = tid & 65535;
    int k = s >> 8, col = s & 255;
    float v = isg ? Wg[s] : Wp[s];
    Wpg_t[(isg ? 256 + col : col) * 256 + k] = packhl(v);
  }
  if (tid < 655360) {  // Wr [512][1280] read-linear, write Wr_t[col][k]
    int k = tid / 1280;
    int col = tid - k * 1280;
    Wr_t[col * 512 + k] = packhl(Wr[tid]);
  }
  if (tid < 65536) {  // zero value-slot 31 via coherent stores (read via MALL)
    cstore32(&vstkH[31 * 65536 + tid], 0u);
    cstoref(&vstkC[31 * 65536 + tid], 0.0f);
  }
  if (do_bar && tid < 512) bar[tid] = 0u;
}

// ---------------------------------------------------------------- plan
// Straight-line register-packed symbolic stack (macros/ternaries only).
#define PGET(p, dst)                                                         \
  {                                                                          \
    u32 wsel = ((p) & 8) ? (((p) & 4) ? t3 : t2) : (((p) & 4) ? t1 : t0);    \
    dst = (int)((wsel >> (((p) & 3) * 8)) & 0xffu);                          \
  }
#define PSET(p, e)                                                           \
  {                                                                          \
    u32 sh_ = (u32)((p) & 3) * 8u;                                           \
    u32 m_ = ~(0xffu << sh_);                                                \
    u32 nv_ = ((u32)(e)) << sh_;                                             \
    int w_ = (p) >> 2;                                                       \
    t0 = (w_ == 0) ? ((t0 & m_) | nv_) : t0;                                 \
    t1 = (w_ == 1) ? ((t1 & m_) | nv_) : t1;                                 \
    t2 = (w_ == 2) ? ((t2 & m_) | nv_) : t2;                                 \
    t3 = (w_ == 3) ? ((t3 & m_) | nv_) : t3;                                 \
  }
#define PDOSTEP(tr, l, r, w)                                                 \
  {                                                                          \
    if ((tr) == 0) {                                                         \
      int pos_ = min(ptr, 15);                                               \
      PSET(pos_, (u32)(bptr & 127));                                         \
      ptr++;                                                                 \
      bptr--;                                                                \
    } else {                                                                 \
      int pl_ = min(max(ptr - 2, 0), 15);                                    \
      int pr_ = min(max(ptr - 1, 0), 15);                                    \
      PGET(pl_, l);                                                          \
      PGET(pr_, r);                                                          \
      u32 v_ = ((verb >> pl_) & 1u) ^ 1u;                                    \
      verb = (verb & ~(1u << pl_)) | (v_ << pl_);                            \
      PSET(pl_, 0x80u | (v_ << 4) | (u32)pl_);                               \
      w = pl_ * 2 + (int)v_;                                                 \
      ptr--;                                                                 \
    }                                                                        \
  }

__global__ __launch_bounds__(256) void plan_kernel(
    const int *__restrict__ trans, int *__restrict__ pL, int *__restrict__ pR,
    int *__restrict__ pW, int *__restrict__ fdesc) {
  int b = threadIdx.x;
  u32 t0 = 0x9F9F9F9Fu, t1 = 0x9F9F9F9Fu, t2 = 0x9F9F9F9Fu, t3 = 0x9F9F9F9Fu;
  u32 verb = 0;
  int ptr = 0, bptr = 127;

  for (int f = 0; f < NPAIR; ++f) {
    int trA = trans[(2 * f) * 256 + b];
    int trB = (2 * f + 1 < 255) ? trans[(2 * f + 1) * 256 + b] : -1;
    int l = 0x9F, r = 0x9F, w = -1;
    PDOSTEP(trA, l, r, w);
    if (trB >= 0) PDOSTEP(trB, l, r, w);
    pL[f * 256 + b] = (l & 0x80) ? (0x8000 | (l & 0x1f)) : l;
    pR[f * 256 + b] = (r & 0x80) ? (0x8000 | (r & 0x1f)) : r;
    pW[f * 256 + b] = w;
  }
  int pf = min(max(ptr - 1, 0), 15);
  int fd;
  PGET(pf, fd);
  fdesc[b] = (fd & 0x80) ? (0x8000 | (fd & 0x1f)) : fd;
}

// ---------------------------------------------------------------- front GEMM
__global__ __launch_bounds__(64) void front_kernel(
    const float *__restrict__ x, const u32 *__restrict__ Wpg,
    const float *__restrict__ bp, const float *__restrict__ bg,
    u32 *__restrict__ h_buf, float *__restrict__ c_buf) {
  const int lane = threadIdx.x;
  const int rbase = blockIdx.x * 16;
  const int y = blockIdx.y;  // 0..3 -> d cols [y*64, y*64+64)
  const int rlo = lane & 15;
  const int khi = (lane >> 4) * 8;

  f32x4 z = {0.f, 0.f, 0.f, 0.f};
  f32x4 aP[4], aG[4];
#pragma unroll
  for (int i = 0; i < 4; i++) { aP[i] = z; aG[i] = z; }

#pragma unroll 2
  for (int kt = 0; kt < 8; ++kt) {
    int k = kt * 32 + khi;
    s16x8 Ah, Al;
    {
      const float *ap = x + (rbase + rlo) * 256 + k;
      float4 v0 = *(const float4 *)ap;
      float4 v1 = *(const float4 *)(ap + 4);
      float w[8] = {v0.x, v0.y, v0.z, v0.w, v1.x, v1.y, v1.z, v1.w};
      split8(w, Ah, Al);
    }
#pragma unroll
    for (int nt = 0; nt < 4; ++nt) {
      int colP = y * 64 + nt * 16 + rlo;
      {
        const u32 *wp = Wpg + colP * 256 + k;
        uint4 q0 = *(const uint4 *)wp, q1 = *(const uint4 *)(wp + 4);
        s16x8 Bh, Bl;
        unpack8(q0, q1, Bh, Bl);
        aP[nt] = MFMA16(Ah, Bh, aP[nt]);
        aP[nt] = MFMA16(Ah, Bl, aP[nt]);
        aP[nt] = MFMA16(Al, Bh, aP[nt]);
      }
      {
        const u32 *wg = Wpg + (256 + colP) * 256 + k;
        uint4 q0 = *(const uint4 *)wg, q1 = *(const uint4 *)(wg + 4);
        s16x8 Bh, Bl;
        unpack8(q0, q1, Bh, Bl);
        aG[nt] = MFMA16(Ah, Bh, aG[nt]);
        aG[nt] = MFMA16(Ah, Bl, aG[nt]);
        aG[nt] = MFMA16(Al, Bh, aG[nt]);
      }
    }
  }
#pragma unroll
  for (int nt = 0; nt < 4; ++nt) {
    int d = y * 64 + nt * 16 + rlo;
    float bpd = bp[d], bgd = bg[d];
#pragma unroll
    for (int ri = 0; ri < 4; ++ri) {
      int r = rbase + (lane >> 4) * 4 + ri;
      float cv = aP[nt][ri] + bpd;
      float gv = aG[nt][ri] + bgd;
      c_buf[r * 256 + d] = cv;
      h_buf[r * 256 + d] = packhl(sigm(gv) * tanhf(cv));
    }
  }
}

// ---------------------------------------------------------------- step body
// COH: per-lane flag — A-source is a vstk value slot (must read via MALL).
#define KSTEP_BODY(SRC, KOFF, COH)                                           \
  {                                                                          \
    const u32 *s = (SRC) + kt * 32 + khi;                                    \
    uint4 a0, a1;                                                            \
    if (COH) {                                                               \
      const u64 *p8 = (const u64 *)s;                                        \
      u64 q0 = cload64(p8), q1 = cload64(p8 + 1);                            \
      u64 q2 = cload64(p8 + 2), q3 = cload64(p8 + 3);                        \
      a0.x = (u32)q0; a0.y = (u32)(q0 >> 32);                                \
      a0.z = (u32)q1; a0.w = (u32)(q1 >> 32);                                \
      a1.x = (u32)q2; a1.y = (u32)(q2 >> 32);                                \
      a1.z = (u32)q3; a1.w = (u32)(q3 >> 32);                                \
    } else {                                                                 \
      a0 = *(const uint4 *)s;                                                \
      a1 = *(const uint4 *)(s + 4);                                          \
    }                                                                        \
    s16x8 Ah, Al;                                                            \
    unpack8(a0, a1, Ah, Al);                                                 \
    int kk = (KOFF) + kt * 32 + khi;                                         \
    {                                                                        \
      const u32 *wp = Wr_t + gcol0 * 512 + kk;                               \
      uint4 q0 = *(const uint4 *)wp, q1 = *(const uint4 *)(wp + 4);          \
      s16x8 Bh, Bl;                                                          \
      unpack8(q0, q1, Bh, Bl);                                               \
      acc0 = MFMA16(Ah, Bh, acc0);                                           \
      acc0 = MFMA16(Ah, Bl, acc0);                                           \
      acc0 = MFMA16(Al, Bh, acc0);                                           \
    }                                                                        \
    {                                                                        \
      const u32 *wp = Wr_t + gcol1 * 512 + kk;                               \
      uint4 q0 = *(const uint4 *)wp, q1 = *(const uint4 *)(wp + 4);          \
      s16x8 Bh, Bl;                                                          \
      unpack8(q0, q1, Bh, Bl);                                               \
      acc1 = MFMA16(Ah, Bh, acc1);                                           \
      acc1 = MFMA16(Ah, Bl, acc1);                                           \
      acc1 = MFMA16(Al, Bh, acc1);                                           \
    }                                                                        \
    {                                                                        \
      const u32 *wp = Wr_t + gcol2 * 512 + kk;                               \
      uint4 q0 = *(const uint4 *)wp, q1 = *(const uint4 *)(wp + 4);          \
      s16x8 Bh, Bl;                                                          \
      unpack8(q0, q1, Bh, Bl);                                               \
      acc2 = MFMA16(Ah, Bh, acc2);                                           \
      acc2 = MFMA16(Ah, Bl, acc2);                                           \
      acc2 = MFMA16(Al, Bh, acc2);                                           \
    }                                                                        \
  }

static __device__ __forceinline__ void step_body(
    int c, int b0, int lane, const float *__restrict__ br,
    const u32 *__restrict__ Wr_t, const u32 *__restrict__ h_buf,
    const float *__restrict__ c_buf, u32 *__restrict__ vstkH,
    float *__restrict__ vstkC, int lc, int rc, int w) {
  const int b = b0 + (lane & 15);
  const bool lval = (lc & 0x8000) != 0;
  const bool rval = (rc & 0x8000) != 0;
  const u32 *srcT = lval ? vstkH + ((vslot(lc) * 256 + b) << 8)
                         : h_buf + (((b << 7) + (lc & 127)) << 8);
  const u32 *srcB = rval ? vstkH + ((vslot(rc) * 256 + b) << 8)
                         : h_buf + (((b << 7) + (rc & 127)) << 8);

  const int khi = (lane >> 4) * 8;
  const int cl = lane & 15;
  const int v2c = 32 + cl;
  const int gcol0 = (cl >> 3) * 256 + c * 8 + (cl & 7);
  const int gcol1 = ((16 + cl) >> 3) * 256 + c * 8 + (cl & 7);
  const int gcol2 = (v2c < 40) ? (v2c >> 3) * 256 + c * 8 + (v2c & 7) : 0;

  f32x4 acc0 = {0.f, 0.f, 0.f, 0.f}, acc1 = acc0, acc2 = acc0;
#pragma unroll 4
  for (int kt = 0; kt < 8; ++kt) KSTEP_BODY(srcT, 0, lval)
#pragma unroll 4
  for (int kt = 0; kt < 8; ++kt) KSTEP_BODY(srcB, 256, rval)

  f32x4 flv, gv;
#pragma unroll
  for (int ri = 0; ri < 4; ++ri) {
    flv[ri] = __shfl_xor(acc0[ri], 8);
    gv[ri] = __shfl_xor(acc1[ri], 8);
  }
  int lcs[4], rcs[4], wcs[4];
#pragma unroll
  for (int ri = 0; ri < 4; ++ri) {
    int rr = (lane >> 4) * 4 + ri;
    lcs[ri] = __shfl(lc, rr);
    rcs[ri] = __shfl(rc, rr);
    wcs[ri] = __shfl(w, rr);
  }
  int colj = lane & 15;
  if (colj < 8) {
    int d = c * 8 + colj;
    float brI = br[d], brFl = br[256 + d], brFr = br[512 + d];
    float brG = br[768 + d], brO = br[1024 + d];
#pragma unroll
    for (int ri = 0; ri < 4; ++ri) {
      if (wcs[ri] >= 0) {
        int b2 = b0 + (lane >> 4) * 4 + ri;
        int lc2 = lcs[ri], rc2 = rcs[ri];
        float c_l = (lc2 & 0x8000)
                        ? cloadf(&vstkC[(vslot(lc2) * 256 + b2) * 256 + d])
                        : c_buf[(b2 * 128 + (lc2 & 127)) * 256 + d];
        float c_r = (rc2 & 0x8000)
                        ? cloadf(&vstkC[(vslot(rc2) * 256 + b2) * 256 + d])
                        : c_buf[(b2 * 128 + (rc2 & 127)) * 256 + d];
        float ii = acc0[ri] + brI;
        float fl = flv[ri] + brFl;
        float fr = acc1[ri] + brFr;
        float gg = gv[ri] + brG;
        float oo = acc2[ri] + brO;
        float cv = sigm(ii) * tanhf(gg) + sigm(fl) * c_l + sigm(fr) * c_r;
        float hv = sigm(oo) * tanhf(cv);
        int sidx = wcs[ri];
        cstore32(&vstkH[(sidx * 256 + b2) * 256 + d], packhl(hv));
        cstoref(&vstkC[(sidx * 256 + b2) * 256 + d], cv);
      }
    }
  }
}

// ---------------------------------------------------------------- scan
// ONE launch. grid (32 chunks, 16 groups), 1 wave/wg (512 wg <= 2/CU).
// Phase separation: group-scoped monotonic counter, relaxed agent atomics,
// NO cache-invalidating fences (vstk traffic is MALL-coherent by itself).
__global__ __launch_bounds__(64) void scan_kernel(
    const float *__restrict__ br, const u32 *__restrict__ Wr_t,
    const u32 *__restrict__ h_buf, const float *__restrict__ c_buf,
    u32 *__restrict__ vstkH, float *__restrict__ vstkC,
    const int *__restrict__ pL, const int *__restrict__ pR,
    const int *__restrict__ pW, u32 *bar) {
  const int c = blockIdx.x;
  const int g = blockIdx.y;
  const int lane = threadIdx.x;
  const int b0 = g * 16;
  u32 *mybar = bar + g * 32;  // 128B-padded per-group counter

  for (int f = 0; f < NPAIR; ++f) {
    int lc = 0, rc = 0, w = -1;
    if (lane < 16) {
      int b = b0 + lane;
      lc = pL[f * 256 + b];
      rc = pR[f * 256 + b];
      w = pW[f * 256 + b];
    }
    lc = __shfl(lc, lane & 15);
    rc = __shfl(rc, lane & 15);
    w = __shfl(w, lane & 15);

    if (__ballot(w >= 0) != 0ull)
      step_body(c, b0, lane, br, Wr_t, h_buf, c_buf, vstkH, vstkC, lc, rc, w);

    // group barrier: drain own (coherent) stores, arrive, spin. No fences.
    asm volatile("s_waitcnt vmcnt(0)" ::: "memory");
    if (lane == 0) {
      __hip_atomic_fetch_add(mybar, 1u, __ATOMIC_RELAXED, __HIP_MEMORY_SCOPE_AGENT);
      u32 tgt = 32u * (u32)(f + 1);
      while (__hip_atomic_load(mybar, __ATOMIC_RELAXED, __HIP_MEMORY_SCOPE_AGENT) < tgt)
        __builtin_amdgcn_s_sleep(2);
    }
    asm volatile("" ::: "memory");
  }
}

// ---------------------------------------------------------------- fallback step
__global__ __launch_bounds__(64) void step_kernel(
    const float *__restrict__ br, const u32 *__restrict__ Wr_t,
    const u32 *__restrict__ h_buf, const float *__restrict__ c_buf,
    u32 *__restrict__ vstkH, float *__restrict__ vstkC,
    const int *__restrict__ pL, const int *__restrict__ pR,
    const int *__restrict__ pW) {
  const int c = blockIdx.x;
  const int b0 = blockIdx.y * 16;
  const int lane = threadIdx.x;
  int lc = 0, rc = 0, w = -1;
  if (lane < 16) {
    int b = b0 + lane;
    lc = pL[b];
    rc = pR[b];
    w = pW[b];
  }
  lc = __shfl(lc, lane & 15);
  rc = __shfl(rc, lane & 15);
  w = __shfl(w, lane & 15);
  if (__ballot(w >= 0) == 0ull) return;
  step_body(c, b0, lane, br, Wr_t, h_buf, c_buf, vstkH, vstkC, lc, rc, w);
}

// ---------------------------------------------------------------- output
__global__ __launch_bounds__(256) void out_kernel(
    const int *__restrict__ fdesc, const u32 *__restrict__ h_buf,
    const u32 *__restrict__ vstkH, float *__restrict__ out) {
  int tid = blockIdx.x * 256 + threadIdx.x;  // 65536
  int b = tid >> 8, d = tid & 255;
  int code = fdesc[b];
  u32 hv = (code & 0x8000)
               ? cload32(&vstkH[(vslot(code) * 256 + b) * 256 + d])
               : h_buf[(b * 128 + (code & 127)) * 256 + d];
  out[tid] = unpackhl(hv);
}

// ---------------------------------------------------------------- launch
extern "C" void kernel_launch(void *const *d_in, const int *in_sizes, int n_in,
                              void *d_out, int out_size, void *d_ws, size_t ws_size,
                              hipStream_t stream) {
  const float *x = (const float *)d_in[0];
  const float *Wp = (const float *)d_in[1];
  const float *bp = (const float *)d_in[2];
  const float *Wg = (const float *)d_in[3];
  const float *bg = (const float *)d_in[4];
  const float *Wr = (const float *)d_in[5];
  const float *br = (const float *)d_in[6];
  const int *trans = (const int *)d_in[7];
  float *out = (float *)d_out;

  char *ws = (char *)d_ws;
  u32 *Wr_t = (u32 *)(ws);
  u32 *Wpg = (u32 *)(ws + 2621440);
  u32 *h_buf = (u32 *)(ws + 3145728);
  float *c_buf = (float *)(ws + 36700160);
  u32 *vstkH = (u32 *)(ws + 70254592);
  float *vstkC = (float *)(ws + 78643200);
  int *planL = (int *)(ws + 87031808);
  int *planR = (int *)(ws + 87162880);
  int *planW = (int *)(ws + 87293952);
  int *fdesc = (int *)(ws + 87425024);
  u32 *bar = (u32 *)(ws + 87426048);

  const int use_scan = (ws_size >= (size_t)87426048 + 2048) ? 1 : 0;

  pack_kernel<<<2560, 256, 0, stream>>>(Wp, Wg, Wr, Wpg, Wr_t, vstkH, vstkC,
                                        bar, use_scan);
  plan_kernel<<<1, 256, 0, stream>>>(trans, planL, planR, planW, fdesc);
  front_kernel<<<dim3(2048, 4), 64, 0, stream>>>(x, Wpg, bp, bg, h_buf, c_buf);

  if (use_scan) {
    scan_kernel<<<dim3(32, 16), 64, 0, stream>>>(br, Wr_t, h_buf, c_buf, vstkH,
                                                 vstkC, planL, planR, planW, bar);
  } else {
    for (int f = 0; f < NPAIR; ++f)
      step_kernel<<<dim3(32, 16), 64, 0, stream>>>(
          br, Wr_t, h_buf, c_buf, vstkH, vstkC, planL + f * 256,
          planR + f * 256, planW + f * 256);
  }
  out_kernel<<<256, 256, 0, stream>>>(fdesc, h_buf, vstkH, out);
}